// Round 3
// baseline (3179.986 us; speedup 1.0000x reference)
//
#include <hip/hip_runtime.h>
#include <math.h>

typedef _Float16 f16;
typedef _Float16 f16x8 __attribute__((ext_vector_type(8)));
typedef float f32x4 __attribute__((ext_vector_type(4)));

#define BATCH   1024
#define HID     1024
#define DIN     64
#define TKNOTS  50
#define FHID    128
#define NSTEPS  50
#define DT_C      0.02f
#define SQRT_DT_C 0.1414213562373095f
#define LO_SCALE  2048.0f
#define INV_LO    4.8828125e-4f   // 1/2048

__device__ __forceinline__ void gload16(const f16* g, const f16* l) {
  __builtin_amdgcn_global_load_lds((const __attribute__((address_space(1))) unsigned int*)g,
                                   (__attribute__((address_space(3))) unsigned int*)l, 16, 0, 0);
}

__device__ __forceinline__ void split_f32(float x, f16& hi, f16& lo) {
  hi = (f16)x;
  lo = (f16)((x - (float)hi) * LO_SCALE);
}

// ---------------------------------------------------------------------------
// g1: h = lipswish(y @ [Wf0|Wg0] + bias), fp16x3 split GEMM.
// C [1024 x 2048] as split f16 pair. Tiles 64x64, BK=32, 4 waves (32x32 each).
// TRIPLE-buffered LDS + counted vmcnt (loads 2 tiles ahead, never drain to 0
// in the main loop) + raw s_barrier. One barrier per K-step.
// ---------------------------------------------------------------------------
__global__ __launch_bounds__(256) void g1_k(
    const f16* __restrict__ Ah, const f16* __restrict__ Al,   // y split [1024][1024]
    const f16* __restrict__ Bh, const f16* __restrict__ Bl,   // Bt0 [2048][1024]
    const float* __restrict__ bias0, const float* __restrict__ bias1,
    f16* __restrict__ Ch, f16* __restrict__ Cl)               // h split [1024][2048]
{
  __shared__ __align__(16) char smem[49152];   // 3 buffers x 16 KB

  const int tid = threadIdx.x;
  const int bid = blockIdx.x;
  const int r   = ((bid & 7) << 6) | (bid >> 3);   // XCD swizzle (512 = 8*64)
  const int m0  = (r & 15) << 6;
  const int n0  = (r >> 4) << 6;

  // staging sources (linear LDS dest o=tid*16; source pre-inverse-swizzled)
  const int sr = tid >> 2;
  const int sc = (((tid & 3) << 4) ^ (((sr >> 1) & 3) << 4)) >> 1;
  const f16* gAh = Ah + (size_t)(m0 + sr) * HID + sc;
  const f16* gAl = Al + (size_t)(m0 + sr) * HID + sc;
  const f16* gBh = Bh + (size_t)(n0 + sr) * HID + sc;
  const f16* gBl = Bl + (size_t)(n0 + sr) * HID + sc;

  // fragment read addressing (swizzled)
  const int lane = tid & 63, wid = tid >> 6;
  const int wm = wid >> 1, wn = wid & 1;
  const int fr = lane & 15, fg = lane >> 4;
  const int kb = (fg << 4) ^ (((fr >> 1) & 3) << 4);
  const int ra0 = (wm * 32 + fr) * 64 + kb, ra1 = ra0 + 1024;
  const int rb0 = (wn * 32 + fr) * 64 + kb, rb1 = rb0 + 1024;

  f32x4 acc1[2][2] = {}, acc2[2][2] = {};

  auto stage = [&](int kt, int b) {
    const int ko = kt << 5;
    char* db = smem + b * 16384 + (tid << 4);
    gload16(gAh + ko, (const f16*)db);
    gload16(gAl + ko, (const f16*)(db + 4096));
    gload16(gBh + ko, (const f16*)(db + 8192));
    gload16(gBl + ko, (const f16*)(db + 12288));
  };

  stage(0, 0);
  stage(1, 1);

  int bsel = 0;
  for (int kt = 0; kt < 32; ++kt) {
    // steady state: 8 of own loads outstanding; keep newest tile's 4 in flight
    if (kt < 31) asm volatile("s_waitcnt vmcnt(4)" ::: "memory");
    else         asm volatile("s_waitcnt vmcnt(0)" ::: "memory");
    __builtin_amdgcn_s_barrier();
    __builtin_amdgcn_sched_barrier(0);   // fence: no LDS-read hoisting above barrier
    if (kt + 2 < 32) { int nb = bsel + 2; if (nb >= 3) nb -= 3; stage(kt + 2, nb); }

    const char* cb = smem + bsel * 16384;
    f16x8 ah0 = *(const f16x8*)(cb + ra0);
    f16x8 ah1 = *(const f16x8*)(cb + ra1);
    f16x8 al0 = *(const f16x8*)(cb + 4096 + ra0);
    f16x8 al1 = *(const f16x8*)(cb + 4096 + ra1);
    f16x8 bh0 = *(const f16x8*)(cb + 8192 + rb0);
    f16x8 bh1 = *(const f16x8*)(cb + 8192 + rb1);
    f16x8 bl0 = *(const f16x8*)(cb + 12288 + rb0);
    f16x8 bl1 = *(const f16x8*)(cb + 12288 + rb1);

    acc1[0][0] = __builtin_amdgcn_mfma_f32_16x16x32_f16(ah0, bh0, acc1[0][0], 0, 0, 0);
    acc1[0][1] = __builtin_amdgcn_mfma_f32_16x16x32_f16(ah0, bh1, acc1[0][1], 0, 0, 0);
    acc1[1][0] = __builtin_amdgcn_mfma_f32_16x16x32_f16(ah1, bh0, acc1[1][0], 0, 0, 0);
    acc1[1][1] = __builtin_amdgcn_mfma_f32_16x16x32_f16(ah1, bh1, acc1[1][1], 0, 0, 0);
    acc2[0][0] = __builtin_amdgcn_mfma_f32_16x16x32_f16(ah0, bl0, acc2[0][0], 0, 0, 0);
    acc2[0][1] = __builtin_amdgcn_mfma_f32_16x16x32_f16(ah0, bl1, acc2[0][1], 0, 0, 0);
    acc2[1][0] = __builtin_amdgcn_mfma_f32_16x16x32_f16(ah1, bl0, acc2[1][0], 0, 0, 0);
    acc2[1][1] = __builtin_amdgcn_mfma_f32_16x16x32_f16(ah1, bl1, acc2[1][1], 0, 0, 0);
    acc2[0][0] = __builtin_amdgcn_mfma_f32_16x16x32_f16(al0, bh0, acc2[0][0], 0, 0, 0);
    acc2[0][1] = __builtin_amdgcn_mfma_f32_16x16x32_f16(al0, bh1, acc2[0][1], 0, 0, 0);
    acc2[1][0] = __builtin_amdgcn_mfma_f32_16x16x32_f16(al1, bh0, acc2[1][0], 0, 0, 0);
    acc2[1][1] = __builtin_amdgcn_mfma_f32_16x16x32_f16(al1, bh1, acc2[1][1], 0, 0, 0);

    bsel = (bsel == 2) ? 0 : bsel + 1;
  }

  // epilogue: bias + lipswish, write split pair
#pragma unroll
  for (int fm = 0; fm < 2; ++fm)
#pragma unroll
    for (int fn = 0; fn < 2; ++fn) {
      const int row = m0 + wm * 32 + fm * 16 + fg * 4;
      const int col = n0 + wn * 32 + fn * 16 + fr;
      const float bs = (col < HID) ? bias0[col] : bias1[col - HID];
#pragma unroll
      for (int rr = 0; rr < 4; ++rr) {
        const float v = acc1[fm][fn][rr] + acc2[fm][fn][rr] * INV_LO + bs;
        const float x = 0.909f * v / (1.0f + expf(-v));
        f16 hi, lo; split_f32(x, hi, lo);
        Ch[(size_t)(row + rr) * 2048 + col] = hi;
        Cl[(size_t)(row + rr) * 2048 + col] = lo;
      }
    }
}

// ---------------------------------------------------------------------------
// g2u: fused layer-2 + Euler-Maruyama update.
// Each block owns a 64x32 (m,n) region; waves 0-1 compute drift = h_f @ Wf1,
// waves 2-3 compute diff = h_g @ Wg1 (wave-tile 32x32 each). Epilogue: diff
// waves publish via LDS; drift waves apply y += dt*drift + sqrt(dt)*dw*diff
// and refresh the y hi/lo split. Double-buffered LDS (2 x 24 KB), R2-proven
// __syncthreads loop (A/B reference against g1's counted-vmcnt schedule).
// ---------------------------------------------------------------------------
__global__ __launch_bounds__(256) void g2u_k(
    const f16* __restrict__ hh_, const f16* __restrict__ hl_,  // h split [1024][2048]
    const f16* __restrict__ B1h, const f16* __restrict__ B1l,  // Bt1 [2048][1024]
    const float* __restrict__ biasf, const float* __restrict__ biasg, // f_bs+H, g_bs+H
    const float* __restrict__ dwk,
    float* __restrict__ y, f16* __restrict__ yh, f16* __restrict__ yl)
{
  __shared__ __align__(16) char smem[49152];   // 2 buffers x 24 KB (+8KB exchange reuse)

  const int tid = threadIdx.x;
  const int bid = blockIdx.x;
  const int r   = ((bid & 7) << 6) | (bid >> 3);
  const int m0  = (r & 15) << 6;        // 16 m-tiles of 64
  const int n0  = (r >> 4) << 5;        // 32 n-tiles of 32

  // A staging (4 x 4KB regions: Af_hi, Af_lo, Ag_hi, Ag_lo)
  const int sr = tid >> 2;
  const int sc = (((tid & 3) << 4) ^ (((sr >> 1) & 3) << 4)) >> 1;
  const f16* gAfh = hh_ + (size_t)(m0 + sr) * 2048 + sc;
  const f16* gAfl = hl_ + (size_t)(m0 + sr) * 2048 + sc;
  const f16* gAgh = gAfh + HID;
  const f16* gAgl = gAfl + HID;
  // B staging (4 x 2KB regions: Bf_hi, Bf_lo, Bg_hi, Bg_lo); 128 threads each
  const int btid = tid & 127;
  const int bsr = btid >> 2;
  const int bsc = (((btid & 3) << 4) ^ (((bsr >> 1) & 3) << 4)) >> 1;
  const f16* Bsel = (tid < 128) ? B1h : B1l;
  const f16* gBf = Bsel + (size_t)(n0 + bsr) * HID + bsc;
  const f16* gBg = Bsel + (size_t)(HID + n0 + bsr) * HID + bsc;
  const int dBoff = 16384 + ((tid >> 7) << 11) + (btid << 4);

  // fragment addressing
  const int lane = tid & 63, wid = tid >> 6;
  const int wm = wid & 1, func = wid >> 1;     // func 0 = drift(f), 1 = diff(g)
  const int fr = lane & 15, fg = lane >> 4;
  const int kb = (fg << 4) ^ (((fr >> 1) & 3) << 4);
  const int Ab = func << 13;                    // A_f @0, A_g @8192 (hi; lo +4096)
  const int ra0 = Ab + (wm * 32 + fr) * 64 + kb, ra1 = ra0 + 1024;
  const int Bb = 16384 + (func << 12);          // B_f @16384, B_g @20480 (hi; lo +2048)
  const int rb0 = Bb + fr * 64 + kb, rb1 = rb0 + 1024;

  f32x4 acc1[2][2] = {}, acc2[2][2] = {};

  auto stage = [&](int kt, int b) {
    const int ko = kt << 5;
    char* db = smem + b * 24576;
    char* da = db + (tid << 4);
    gload16(gAfh + ko, (const f16*)da);
    gload16(gAfl + ko, (const f16*)(da + 4096));
    gload16(gAgh + ko, (const f16*)(da + 8192));
    gload16(gAgl + ko, (const f16*)(da + 12288));
    gload16(gBf + ko, (const f16*)(db + dBoff));
    gload16(gBg + ko, (const f16*)(db + dBoff + 4096));
  };

  stage(0, 0);
  __syncthreads();

  int cur = 0;
  for (int kt = 0; kt < 32; ++kt) {
    if (kt < 31) stage(kt + 1, cur ^ 1);

    const char* cb = smem + cur * 24576;
    f16x8 ah0 = *(const f16x8*)(cb + ra0);
    f16x8 ah1 = *(const f16x8*)(cb + ra1);
    f16x8 al0 = *(const f16x8*)(cb + ra0 + 4096);
    f16x8 al1 = *(const f16x8*)(cb + ra1 + 4096);
    f16x8 bh0 = *(const f16x8*)(cb + rb0);
    f16x8 bh1 = *(const f16x8*)(cb + rb1);
    f16x8 bl0 = *(const f16x8*)(cb + rb0 + 2048);
    f16x8 bl1 = *(const f16x8*)(cb + rb1 + 2048);

    acc1[0][0] = __builtin_amdgcn_mfma_f32_16x16x32_f16(ah0, bh0, acc1[0][0], 0, 0, 0);
    acc1[0][1] = __builtin_amdgcn_mfma_f32_16x16x32_f16(ah0, bh1, acc1[0][1], 0, 0, 0);
    acc1[1][0] = __builtin_amdgcn_mfma_f32_16x16x32_f16(ah1, bh0, acc1[1][0], 0, 0, 0);
    acc1[1][1] = __builtin_amdgcn_mfma_f32_16x16x32_f16(ah1, bh1, acc1[1][1], 0, 0, 0);
    acc2[0][0] = __builtin_amdgcn_mfma_f32_16x16x32_f16(ah0, bl0, acc2[0][0], 0, 0, 0);
    acc2[0][1] = __builtin_amdgcn_mfma_f32_16x16x32_f16(ah0, bl1, acc2[0][1], 0, 0, 0);
    acc2[1][0] = __builtin_amdgcn_mfma_f32_16x16x32_f16(ah1, bl0, acc2[1][0], 0, 0, 0);
    acc2[1][1] = __builtin_amdgcn_mfma_f32_16x16x32_f16(ah1, bl1, acc2[1][1], 0, 0, 0);
    acc2[0][0] = __builtin_amdgcn_mfma_f32_16x16x32_f16(al0, bh0, acc2[0][0], 0, 0, 0);
    acc2[0][1] = __builtin_amdgcn_mfma_f32_16x16x32_f16(al0, bh1, acc2[0][1], 0, 0, 0);
    acc2[1][0] = __builtin_amdgcn_mfma_f32_16x16x32_f16(al1, bh0, acc2[1][0], 0, 0, 0);
    acc2[1][1] = __builtin_amdgcn_mfma_f32_16x16x32_f16(al1, bh1, acc2[1][1], 0, 0, 0);

    __syncthreads();
    cur ^= 1;
  }

  // epilogue: exchange diff via LDS, then fused Euler-Maruyama update
  float* ex = (float*)smem;   // [2][32][32] f32 = 8 KB, reuses buffer 0
  if (func == 1) {
#pragma unroll
    for (int fm = 0; fm < 2; ++fm)
#pragma unroll
      for (int fn = 0; fn < 2; ++fn)
#pragma unroll
        for (int rr = 0; rr < 4; ++rr) {
          const int lr = fm * 16 + fg * 4 + rr;
          const int lc = fn * 16 + fr;
          const float v = acc1[fm][fn][rr] + acc2[fm][fn][rr] * INV_LO + biasg[n0 + lc];
          ex[wm * 1024 + lr * 32 + lc] = v;
        }
  }
  __syncthreads();
  if (func == 0) {
#pragma unroll
    for (int fm = 0; fm < 2; ++fm)
#pragma unroll
      for (int fn = 0; fn < 2; ++fn)
#pragma unroll
        for (int rr = 0; rr < 4; ++rr) {
          const int lr = fm * 16 + fg * 4 + rr;
          const int lc = fn * 16 + fr;
          const int row = m0 + wm * 32 + lr;
          const int col = n0 + lc;
          const float drift = acc1[fm][fn][rr] + acc2[fm][fn][rr] * INV_LO + biasf[col];
          const float diff  = ex[wm * 1024 + lr * 32 + lc];
          const size_t idx  = (size_t)row * HID + col;
          // exact same fma order as the old update_y kernel (bit-identical y)
          const float yn = fmaf(DT_C, drift, fmaf(SQRT_DT_C * dwk[idx], diff, y[idx]));
          y[idx] = yn;
          f16 hi, lo; split_f32(yn, hi, lo);
          yh[idx] = hi;
          yl[idx] = lo;
        }
  }
}

// ---------------------------------------------------------------------------
// weight prep: split+transpose W[k][n] (fp32) -> Bt_hi/lo[n][k] (f16).
// ---------------------------------------------------------------------------
__global__ __launch_bounds__(256) void split_transpose_k(
    const float* __restrict__ f_ws, const float* __restrict__ g_ws,
    f16* __restrict__ Bt0h, f16* __restrict__ Bt0l,
    f16* __restrict__ Bt1h, f16* __restrict__ Bt1l)
{
  __shared__ float t[32][33];
  const int z = blockIdx.z;
  const float* src = (z & 1) ? g_ws : f_ws;
  if (z >= 2) src += (size_t)HID * HID;
  f16* dh = (z >= 2) ? Bt1h : Bt0h;
  f16* dl = (z >= 2) ? Bt1l : Bt0l;
  const int nb = (z & 1) ? HID : 0;

  const int tx = threadIdx.x, ty = threadIdx.y;
  const int k0 = blockIdx.y * 32, n0 = blockIdx.x * 32;
#pragma unroll
  for (int i = 0; i < 4; ++i)
    t[ty + i * 8][tx] = src[(size_t)(k0 + ty + i * 8) * HID + n0 + tx];
  __syncthreads();
#pragma unroll
  for (int i = 0; i < 4; ++i) {
    const int n = n0 + ty + i * 8;
    const int k = k0 + tx;
    f16 hi, lo; split_f32(t[tx][ty + i * 8], hi, lo);
    dh[(size_t)(nb + n) * HID + k] = hi;
    dl[(size_t)(nb + n) * HID + k] = lo;
  }
}

// y0[b,j] = coeffs[b,0,:] @ initial_w + initial_b  (+ split outputs)
__global__ __launch_bounds__(256) void y0_k(
    const float* __restrict__ coeffs, const float* __restrict__ w,
    const float* __restrict__ b, float* __restrict__ y,
    f16* __restrict__ yh, f16* __restrict__ yl)
{
  __shared__ float c[DIN];
  const int bi = blockIdx.x;
  if (threadIdx.x < DIN) c[threadIdx.x] = coeffs[(size_t)bi * (TKNOTS * DIN) + threadIdx.x];
  __syncthreads();
#pragma unroll
  for (int rr = 0; rr < 4; ++rr) {
    const int j = threadIdx.x + rr * 256;
    float s = b[j];
#pragma unroll 8
    for (int d = 0; d < DIN; ++d) s = fmaf(c[d], w[(size_t)d * HID + j], s);
    y[(size_t)bi * HID + j] = s;
    f16 hi, lo; split_f32(s, hi, lo);
    yh[(size_t)bi * HID + j] = hi;
    yl[(size_t)bi * HID + j] = lo;
  }
}

// ---------------- fp32 decoder (small share) ----------
#define BM 64
#define BN 64
#define BK 32
#define MODE_LIN  0
#define MODE_RELU 2

__global__ __launch_bounds__(256) void gemm_k(
    const float* __restrict__ A, int lda,
    const float* __restrict__ B0, int ldb,
    const float* __restrict__ bias0,
    float* __restrict__ C, int ldc, int K, int mode)
{
  __shared__ float As[BK][BM];
  __shared__ float Bs[BK][BN];
  const int t  = threadIdx.x;
  const int m0 = blockIdx.y * BM;
  const int n0 = blockIdx.x * BN;
  const int ar = t >> 3, ac = (t & 7) << 2;
  const int br = t >> 4, bc = (t & 15) << 2;
  const int i0 = (t >> 4) << 2, j0 = (t & 15) << 2;
  float acc[4][4];
#pragma unroll
  for (int rr = 0; rr < 4; ++rr)
#pragma unroll
    for (int c = 0; c < 4; ++c) acc[rr][c] = 0.0f;

  for (int k0 = 0; k0 < K; k0 += BK) {
    const float4 a0 = *(const float4*)(A + (size_t)(m0 + ar)      * lda + k0 + ac);
    const float4 a1 = *(const float4*)(A + (size_t)(m0 + ar + 32) * lda + k0 + ac);
    const float4 b0 = *(const float4*)(B0 + (size_t)(k0 + br)      * ldb + n0 + bc);
    const float4 b1 = *(const float4*)(B0 + (size_t)(k0 + br + 16) * ldb + n0 + bc);
    __syncthreads();
    As[ac + 0][ar] = a0.x; As[ac + 1][ar] = a0.y; As[ac + 2][ar] = a0.z; As[ac + 3][ar] = a0.w;
    As[ac + 0][ar + 32] = a1.x; As[ac + 1][ar + 32] = a1.y;
    As[ac + 2][ar + 32] = a1.z; As[ac + 3][ar + 32] = a1.w;
    *(float4*)&Bs[br][bc] = b0;
    *(float4*)&Bs[br + 16][bc] = b1;
    __syncthreads();
#pragma unroll
    for (int kk = 0; kk < BK; ++kk) {
      const float4 av = *(const float4*)&As[kk][i0];
      const float4 bv = *(const float4*)&Bs[kk][j0];
      const float a_[4] = {av.x, av.y, av.z, av.w};
      const float b_[4] = {bv.x, bv.y, bv.z, bv.w};
#pragma unroll
      for (int rr = 0; rr < 4; ++rr)
#pragma unroll
        for (int c = 0; c < 4; ++c)
          acc[rr][c] = fmaf(a_[rr], b_[c], acc[rr][c]);
    }
  }
#pragma unroll
  for (int rr = 0; rr < 4; ++rr) {
    float4 v; float* vp = &v.x;
#pragma unroll
    for (int c = 0; c < 4; ++c) {
      float x = acc[rr][c] + bias0[n0 + j0 + c];
      if (mode == MODE_RELU) x = fmaxf(x, 0.0f);
      vp[c] = x;
    }
    *(float4*)(C + (size_t)(m0 + i0 + rr) * ldc + n0 + j0) = v;
  }
}

__global__ __launch_bounds__(256) void tvec_k(
    const float* __restrict__ emb_w, const float* __restrict__ emb_b,
    float* __restrict__ tv)
{
  const int j = blockIdx.x * 256 + threadIdx.x;
  float s = emb_b[j];
#pragma unroll 8
  for (int k = 0; k < FHID; ++k)
    s = fmaf((float)k * (1.0f / 127.0f), emb_w[(size_t)(FHID + k) * HID + j], s);
  tv[j] = s;
}

// ---------------------------------------------------------------------------
extern "C" void kernel_launch(void* const* d_in, const int* in_sizes, int n_in,
                              void* d_out, int out_size, void* d_ws, size_t ws_size,
                              hipStream_t stream) {
  const float* coeffs    = (const float*)d_in[0];
  const float* dw        = (const float*)d_in[2];
  const float* f_ws      = (const float*)d_in[3];
  const float* f_bs      = (const float*)d_in[4];
  const float* g_ws      = (const float*)d_in[5];
  const float* g_bs      = (const float*)d_in[6];
  const float* initial_w = (const float*)d_in[7];
  const float* initial_b = (const float*)d_in[8];
  const float* lin_in_w  = (const float*)d_in[9];
  const float* lin_in_b  = (const float*)d_in[10];
  const float* emb_w     = (const float*)d_in[11];
  const float* emb_b     = (const float*)d_in[12];
  const float* samp_w    = (const float*)d_in[13];
  const float* samp_b    = (const float*)d_in[14];
  float* out = (float*)d_out;

  char* ws = (char*)d_ws;
  f16*   Bt0h = (f16*)(ws);                       // 4 MB [2048][1024]
  f16*   Bt0l = (f16*)(ws + (4u << 20));
  f16*   Bt1h = (f16*)(ws + (8u << 20));
  f16*   Bt1l = (f16*)(ws + (12u << 20));
  f16*   yh   = (f16*)(ws + (16u << 20));         // 2 MB
  f16*   yl   = (f16*)(ws + (18u << 20));
  f16*   hh   = (f16*)(ws + (20u << 20));         // 4 MB [1024][2048]
  f16*   hl   = (f16*)(ws + (24u << 20));
  float* y    = (float*)(ws + (28u << 20));       // 4 MB
  float* z1   = (float*)(ws + (32u << 20));       // 512 KB
  float* z2   = (float*)(ws + (33u << 20));       // 4 MB
  float* tv   = (float*)(ws + (37u << 20));       // 4 KB

  split_transpose_k<<<dim3(HID / 32, HID / 32, 4), dim3(32, 8), 0, stream>>>(
      f_ws, g_ws, Bt0h, Bt0l, Bt1h, Bt1l);

  y0_k<<<BATCH, 256, 0, stream>>>(coeffs, initial_w, initial_b, y, yh, yl);

  for (int k = 0; k < NSTEPS; ++k) {
    g1_k<<<512, 256, 0, stream>>>(yh, yl, Bt0h, Bt0l, f_bs, g_bs, hh, hl);
    g2u_k<<<512, 256, 0, stream>>>(hh, hl, Bt1h, Bt1l, f_bs + HID, g_bs + HID,
                                   dw + (size_t)k * BATCH * HID, y, yh, yl);
  }

  // decoder
  gemm_k<<<dim3(FHID / BN, BATCH / BM), 256, 0, stream>>>(
      y, HID, lin_in_w, FHID, lin_in_b, z1, FHID, HID, MODE_RELU);
  tvec_k<<<HID / 256, 256, 0, stream>>>(emb_w, emb_b, tv);
  gemm_k<<<dim3(HID / BN, BATCH / BM), 256, 0, stream>>>(
      z1, FHID, emb_w, HID, tv, z2, HID, FHID, MODE_RELU);
  gemm_k<<<dim3(FHID / BN, BATCH / BM), 256, 0, stream>>>(
      z2, HID, samp_w, FHID, samp_b, out, FHID, HID, MODE_LIN);
}

// Round 4
// 3176.897 us; speedup vs baseline: 1.0010x; 1.0010x over previous
//
#include <hip/hip_runtime.h>
#include <math.h>

typedef _Float16 f16;
typedef _Float16 f16x8 __attribute__((ext_vector_type(8)));
typedef float f32x4 __attribute__((ext_vector_type(4)));

#define BATCH   1024
#define HID     1024
#define DIN     64
#define TKNOTS  50
#define FHID    128
#define NSTEPS  50
#define DT_C      0.02f
#define SQRT_DT_C 0.1414213562373095f
#define LO_SCALE  2048.0f
#define INV_LO    4.8828125e-4f   // 1/2048

__device__ __forceinline__ void gload16(const f16* g, const f16* l) {
  __builtin_amdgcn_global_load_lds((const __attribute__((address_space(1))) unsigned int*)g,
                                   (__attribute__((address_space(3))) unsigned int*)l, 16, 0, 0);
}

__device__ __forceinline__ void split_f32(float x, f16& hi, f16& lo) {
  hi = (f16)x;
  lo = (f16)((x - (float)hi) * LO_SCALE);
}

// ---------------------------------------------------------------------------
// g1: h = lipswish(y @ [Wf0|Wg0] + bias), fp16x3 split GEMM.
// R2-PROVEN STRUCTURE (reverted from R3's counted-vmcnt experiment):
// 64x64 tiles, BK=32, 4 waves (32x32 each), 2x16KB double-buffered LDS,
// stage-next-at-top, ONE __syncthreads per K-step, no inline asm.
// ---------------------------------------------------------------------------
__global__ __launch_bounds__(256) void g1_k(
    const f16* __restrict__ Ah, const f16* __restrict__ Al,   // y split [1024][1024]
    const f16* __restrict__ Bh, const f16* __restrict__ Bl,   // Bt0 [2048][1024]
    const float* __restrict__ bias0, const float* __restrict__ bias1,
    f16* __restrict__ Ch, f16* __restrict__ Cl)               // h split [1024][2048]
{
  __shared__ __align__(16) char smem[32768];   // 2 buffers x 16 KB

  const int tid = threadIdx.x;
  const int bid = blockIdx.x;
  const int r   = ((bid & 7) << 6) | (bid >> 3);   // XCD swizzle (512 = 8*64)
  const int m0  = (r & 15) << 6;
  const int n0  = (r >> 4) << 6;

  // staging sources (linear LDS dest o=tid*16; source pre-inverse-swizzled)
  const int sr = tid >> 2;
  const int sc = (((tid & 3) << 4) ^ (((sr >> 1) & 3) << 4)) >> 1;
  const f16* gAh = Ah + (size_t)(m0 + sr) * HID + sc;
  const f16* gAl = Al + (size_t)(m0 + sr) * HID + sc;
  const f16* gBh = Bh + (size_t)(n0 + sr) * HID + sc;
  const f16* gBl = Bl + (size_t)(n0 + sr) * HID + sc;

  // fragment read addressing (swizzled)
  const int lane = tid & 63, wid = tid >> 6;
  const int wm = wid >> 1, wn = wid & 1;
  const int fr = lane & 15, fg = lane >> 4;
  const int kb = (fg << 4) ^ (((fr >> 1) & 3) << 4);
  const int ra0 = (wm * 32 + fr) * 64 + kb, ra1 = ra0 + 1024;
  const int rb0 = (wn * 32 + fr) * 64 + kb, rb1 = rb0 + 1024;

  f32x4 acc1[2][2] = {}, acc2[2][2] = {};

  auto stage = [&](int kt, int b) {
    const int ko = kt << 5;
    char* db = smem + b * 16384 + (tid << 4);
    gload16(gAh + ko, (const f16*)db);
    gload16(gAl + ko, (const f16*)(db + 4096));
    gload16(gBh + ko, (const f16*)(db + 8192));
    gload16(gBl + ko, (const f16*)(db + 12288));
  };

  stage(0, 0);
  __syncthreads();

  int cur = 0;
  for (int kt = 0; kt < 32; ++kt) {
    if (kt < 31) stage(kt + 1, cur ^ 1);

    const char* cb = smem + cur * 16384;
    f16x8 ah0 = *(const f16x8*)(cb + ra0);
    f16x8 ah1 = *(const f16x8*)(cb + ra1);
    f16x8 al0 = *(const f16x8*)(cb + 4096 + ra0);
    f16x8 al1 = *(const f16x8*)(cb + 4096 + ra1);
    f16x8 bh0 = *(const f16x8*)(cb + 8192 + rb0);
    f16x8 bh1 = *(const f16x8*)(cb + 8192 + rb1);
    f16x8 bl0 = *(const f16x8*)(cb + 12288 + rb0);
    f16x8 bl1 = *(const f16x8*)(cb + 12288 + rb1);

    acc1[0][0] = __builtin_amdgcn_mfma_f32_16x16x32_f16(ah0, bh0, acc1[0][0], 0, 0, 0);
    acc1[0][1] = __builtin_amdgcn_mfma_f32_16x16x32_f16(ah0, bh1, acc1[0][1], 0, 0, 0);
    acc1[1][0] = __builtin_amdgcn_mfma_f32_16x16x32_f16(ah1, bh0, acc1[1][0], 0, 0, 0);
    acc1[1][1] = __builtin_amdgcn_mfma_f32_16x16x32_f16(ah1, bh1, acc1[1][1], 0, 0, 0);
    acc2[0][0] = __builtin_amdgcn_mfma_f32_16x16x32_f16(ah0, bl0, acc2[0][0], 0, 0, 0);
    acc2[0][1] = __builtin_amdgcn_mfma_f32_16x16x32_f16(ah0, bl1, acc2[0][1], 0, 0, 0);
    acc2[1][0] = __builtin_amdgcn_mfma_f32_16x16x32_f16(ah1, bl0, acc2[1][0], 0, 0, 0);
    acc2[1][1] = __builtin_amdgcn_mfma_f32_16x16x32_f16(ah1, bl1, acc2[1][1], 0, 0, 0);
    acc2[0][0] = __builtin_amdgcn_mfma_f32_16x16x32_f16(al0, bh0, acc2[0][0], 0, 0, 0);
    acc2[0][1] = __builtin_amdgcn_mfma_f32_16x16x32_f16(al0, bh1, acc2[0][1], 0, 0, 0);
    acc2[1][0] = __builtin_amdgcn_mfma_f32_16x16x32_f16(al1, bh0, acc2[1][0], 0, 0, 0);
    acc2[1][1] = __builtin_amdgcn_mfma_f32_16x16x32_f16(al1, bh1, acc2[1][1], 0, 0, 0);

    __syncthreads();
    cur ^= 1;
  }

  // epilogue: bias + lipswish, write split pair
#pragma unroll
  for (int fm = 0; fm < 2; ++fm)
#pragma unroll
    for (int fn = 0; fn < 2; ++fn) {
      const int row = m0 + wm * 32 + fm * 16 + fg * 4;
      const int col = n0 + wn * 32 + fn * 16 + fr;
      const float bs = (col < HID) ? bias0[col] : bias1[col - HID];
#pragma unroll
      for (int rr = 0; rr < 4; ++rr) {
        const float v = acc1[fm][fn][rr] + acc2[fm][fn][rr] * INV_LO + bs;
        const float x = 0.909f * v / (1.0f + expf(-v));
        f16 hi, lo; split_f32(x, hi, lo);
        Ch[(size_t)(row + rr) * 2048 + col] = hi;
        Cl[(size_t)(row + rr) * 2048 + col] = lo;
      }
    }
}

// ---------------------------------------------------------------------------
// g2u: fused layer-2 + Euler-Maruyama update (unchanged from R3; passed).
// Each block owns a 64x32 (m,n) region; waves 0-1 compute drift = h_f @ Wf1,
// waves 2-3 compute diff = h_g @ Wg1. Epilogue: diff waves publish via LDS;
// drift waves apply y += dt*drift + sqrt(dt)*dw*diff and refresh y hi/lo.
// ---------------------------------------------------------------------------
__global__ __launch_bounds__(256) void g2u_k(
    const f16* __restrict__ hh_, const f16* __restrict__ hl_,  // h split [1024][2048]
    const f16* __restrict__ B1h, const f16* __restrict__ B1l,  // Bt1 [2048][1024]
    const float* __restrict__ biasf, const float* __restrict__ biasg,
    const float* __restrict__ dwk,
    float* __restrict__ y, f16* __restrict__ yh, f16* __restrict__ yl)
{
  __shared__ __align__(16) char smem[49152];   // 2 buffers x 24 KB

  const int tid = threadIdx.x;
  const int bid = blockIdx.x;
  const int r   = ((bid & 7) << 6) | (bid >> 3);
  const int m0  = (r & 15) << 6;        // 16 m-tiles of 64
  const int n0  = (r >> 4) << 5;        // 32 n-tiles of 32

  // A staging (4 x 4KB regions: Af_hi, Af_lo, Ag_hi, Ag_lo)
  const int sr = tid >> 2;
  const int sc = (((tid & 3) << 4) ^ (((sr >> 1) & 3) << 4)) >> 1;
  const f16* gAfh = hh_ + (size_t)(m0 + sr) * 2048 + sc;
  const f16* gAfl = hl_ + (size_t)(m0 + sr) * 2048 + sc;
  const f16* gAgh = gAfh + HID;
  const f16* gAgl = gAfl + HID;
  // B staging (4 x 2KB regions); 128 threads each
  const int btid = tid & 127;
  const int bsr = btid >> 2;
  const int bsc = (((btid & 3) << 4) ^ (((bsr >> 1) & 3) << 4)) >> 1;
  const f16* Bsel = (tid < 128) ? B1h : B1l;
  const f16* gBf = Bsel + (size_t)(n0 + bsr) * HID + bsc;
  const f16* gBg = Bsel + (size_t)(HID + n0 + bsr) * HID + bsc;
  const int dBoff = 16384 + ((tid >> 7) << 11) + (btid << 4);

  // fragment addressing
  const int lane = tid & 63, wid = tid >> 6;
  const int wm = wid & 1, func = wid >> 1;     // func 0 = drift(f), 1 = diff(g)
  const int fr = lane & 15, fg = lane >> 4;
  const int kb = (fg << 4) ^ (((fr >> 1) & 3) << 4);
  const int Ab = func << 13;
  const int ra0 = Ab + (wm * 32 + fr) * 64 + kb, ra1 = ra0 + 1024;
  const int Bb = 16384 + (func << 12);
  const int rb0 = Bb + fr * 64 + kb, rb1 = rb0 + 1024;

  f32x4 acc1[2][2] = {}, acc2[2][2] = {};

  auto stage = [&](int kt, int b) {
    const int ko = kt << 5;
    char* db = smem + b * 24576;
    char* da = db + (tid << 4);
    gload16(gAfh + ko, (const f16*)da);
    gload16(gAfl + ko, (const f16*)(da + 4096));
    gload16(gAgh + ko, (const f16*)(da + 8192));
    gload16(gAgl + ko, (const f16*)(da + 12288));
    gload16(gBf + ko, (const f16*)(db + dBoff));
    gload16(gBg + ko, (const f16*)(db + dBoff + 4096));
  };

  stage(0, 0);
  __syncthreads();

  int cur = 0;
  for (int kt = 0; kt < 32; ++kt) {
    if (kt < 31) stage(kt + 1, cur ^ 1);

    const char* cb = smem + cur * 24576;
    f16x8 ah0 = *(const f16x8*)(cb + ra0);
    f16x8 ah1 = *(const f16x8*)(cb + ra1);
    f16x8 al0 = *(const f16x8*)(cb + ra0 + 4096);
    f16x8 al1 = *(const f16x8*)(cb + ra1 + 4096);
    f16x8 bh0 = *(const f16x8*)(cb + rb0);
    f16x8 bh1 = *(const f16x8*)(cb + rb1);
    f16x8 bl0 = *(const f16x8*)(cb + rb0 + 2048);
    f16x8 bl1 = *(const f16x8*)(cb + rb1 + 2048);

    acc1[0][0] = __builtin_amdgcn_mfma_f32_16x16x32_f16(ah0, bh0, acc1[0][0], 0, 0, 0);
    acc1[0][1] = __builtin_amdgcn_mfma_f32_16x16x32_f16(ah0, bh1, acc1[0][1], 0, 0, 0);
    acc1[1][0] = __builtin_amdgcn_mfma_f32_16x16x32_f16(ah1, bh0, acc1[1][0], 0, 0, 0);
    acc1[1][1] = __builtin_amdgcn_mfma_f32_16x16x32_f16(ah1, bh1, acc1[1][1], 0, 0, 0);
    acc2[0][0] = __builtin_amdgcn_mfma_f32_16x16x32_f16(ah0, bl0, acc2[0][0], 0, 0, 0);
    acc2[0][1] = __builtin_amdgcn_mfma_f32_16x16x32_f16(ah0, bl1, acc2[0][1], 0, 0, 0);
    acc2[1][0] = __builtin_amdgcn_mfma_f32_16x16x32_f16(ah1, bl0, acc2[1][0], 0, 0, 0);
    acc2[1][1] = __builtin_amdgcn_mfma_f32_16x16x32_f16(ah1, bl1, acc2[1][1], 0, 0, 0);
    acc2[0][0] = __builtin_amdgcn_mfma_f32_16x16x32_f16(al0, bh0, acc2[0][0], 0, 0, 0);
    acc2[0][1] = __builtin_amdgcn_mfma_f32_16x16x32_f16(al0, bh1, acc2[0][1], 0, 0, 0);
    acc2[1][0] = __builtin_amdgcn_mfma_f32_16x16x32_f16(al1, bh0, acc2[1][0], 0, 0, 0);
    acc2[1][1] = __builtin_amdgcn_mfma_f32_16x16x32_f16(al1, bh1, acc2[1][1], 0, 0, 0);

    __syncthreads();
    cur ^= 1;
  }

  // epilogue: exchange diff via LDS, then fused Euler-Maruyama update
  float* ex = (float*)smem;   // [2][32][32] f32 = 8 KB, reuses buffer 0
  if (func == 1) {
#pragma unroll
    for (int fm = 0; fm < 2; ++fm)
#pragma unroll
      for (int fn = 0; fn < 2; ++fn)
#pragma unroll
        for (int rr = 0; rr < 4; ++rr) {
          const int lr = fm * 16 + fg * 4 + rr;
          const int lc = fn * 16 + fr;
          const float v = acc1[fm][fn][rr] + acc2[fm][fn][rr] * INV_LO + biasg[n0 + lc];
          ex[wm * 1024 + lr * 32 + lc] = v;
        }
  }
  __syncthreads();
  if (func == 0) {
#pragma unroll
    for (int fm = 0; fm < 2; ++fm)
#pragma unroll
      for (int fn = 0; fn < 2; ++fn)
#pragma unroll
        for (int rr = 0; rr < 4; ++rr) {
          const int lr = fm * 16 + fg * 4 + rr;
          const int lc = fn * 16 + fr;
          const int row = m0 + wm * 32 + lr;
          const int col = n0 + lc;
          const float drift = acc1[fm][fn][rr] + acc2[fm][fn][rr] * INV_LO + biasf[col];
          const float diff  = ex[wm * 1024 + lr * 32 + lc];
          const size_t idx  = (size_t)row * HID + col;
          const float yn = fmaf(DT_C, drift, fmaf(SQRT_DT_C * dwk[idx], diff, y[idx]));
          y[idx] = yn;
          f16 hi, lo; split_f32(yn, hi, lo);
          yh[idx] = hi;
          yl[idx] = lo;
        }
  }
}

// ---------------------------------------------------------------------------
// weight prep: split+transpose W[k][n] (fp32) -> Bt_hi/lo[n][k] (f16).
// ---------------------------------------------------------------------------
__global__ __launch_bounds__(256) void split_transpose_k(
    const float* __restrict__ f_ws, const float* __restrict__ g_ws,
    f16* __restrict__ Bt0h, f16* __restrict__ Bt0l,
    f16* __restrict__ Bt1h, f16* __restrict__ Bt1l)
{
  __shared__ float t[32][33];
  const int z = blockIdx.z;
  const float* src = (z & 1) ? g_ws : f_ws;
  if (z >= 2) src += (size_t)HID * HID;
  f16* dh = (z >= 2) ? Bt1h : Bt0h;
  f16* dl = (z >= 2) ? Bt1l : Bt0l;
  const int nb = (z & 1) ? HID : 0;

  const int tx = threadIdx.x, ty = threadIdx.y;
  const int k0 = blockIdx.y * 32, n0 = blockIdx.x * 32;
#pragma unroll
  for (int i = 0; i < 4; ++i)
    t[ty + i * 8][tx] = src[(size_t)(k0 + ty + i * 8) * HID + n0 + tx];
  __syncthreads();
#pragma unroll
  for (int i = 0; i < 4; ++i) {
    const int n = n0 + ty + i * 8;
    const int k = k0 + tx;
    f16 hi, lo; split_f32(t[tx][ty + i * 8], hi, lo);
    dh[(size_t)(nb + n) * HID + k] = hi;
    dl[(size_t)(nb + n) * HID + k] = lo;
  }
}

// y0[b,j] = coeffs[b,0,:] @ initial_w + initial_b  (+ split outputs)
__global__ __launch_bounds__(256) void y0_k(
    const float* __restrict__ coeffs, const float* __restrict__ w,
    const float* __restrict__ b, float* __restrict__ y,
    f16* __restrict__ yh, f16* __restrict__ yl)
{
  __shared__ float c[DIN];
  const int bi = blockIdx.x;
  if (threadIdx.x < DIN) c[threadIdx.x] = coeffs[(size_t)bi * (TKNOTS * DIN) + threadIdx.x];
  __syncthreads();
#pragma unroll
  for (int rr = 0; rr < 4; ++rr) {
    const int j = threadIdx.x + rr * 256;
    float s = b[j];
#pragma unroll 8
    for (int d = 0; d < DIN; ++d) s = fmaf(c[d], w[(size_t)d * HID + j], s);
    y[(size_t)bi * HID + j] = s;
    f16 hi, lo; split_f32(s, hi, lo);
    yh[(size_t)bi * HID + j] = hi;
    yl[(size_t)bi * HID + j] = lo;
  }
}

// ---------------- fp32 decoder (small share) ----------
#define BM 64
#define BN 64
#define BK 32
#define MODE_LIN  0
#define MODE_RELU 2

__global__ __launch_bounds__(256) void gemm_k(
    const float* __restrict__ A, int lda,
    const float* __restrict__ B0, int ldb,
    const float* __restrict__ bias0,
    float* __restrict__ C, int ldc, int K, int mode)
{
  __shared__ float As[BK][BM];
  __shared__ float Bs[BK][BN];
  const int t  = threadIdx.x;
  const int m0 = blockIdx.y * BM;
  const int n0 = blockIdx.x * BN;
  const int ar = t >> 3, ac = (t & 7) << 2;
  const int br = t >> 4, bc = (t & 15) << 2;
  const int i0 = (t >> 4) << 2, j0 = (t & 15) << 2;
  float acc[4][4];
#pragma unroll
  for (int rr = 0; rr < 4; ++rr)
#pragma unroll
    for (int c = 0; c < 4; ++c) acc[rr][c] = 0.0f;

  for (int k0 = 0; k0 < K; k0 += BK) {
    const float4 a0 = *(const float4*)(A + (size_t)(m0 + ar)      * lda + k0 + ac);
    const float4 a1 = *(const float4*)(A + (size_t)(m0 + ar + 32) * lda + k0 + ac);
    const float4 b0 = *(const float4*)(B0 + (size_t)(k0 + br)      * ldb + n0 + bc);
    const float4 b1 = *(const float4*)(B0 + (size_t)(k0 + br + 16) * ldb + n0 + bc);
    __syncthreads();
    As[ac + 0][ar] = a0.x; As[ac + 1][ar] = a0.y; As[ac + 2][ar] = a0.z; As[ac + 3][ar] = a0.w;
    As[ac + 0][ar + 32] = a1.x; As[ac + 1][ar + 32] = a1.y;
    As[ac + 2][ar + 32] = a1.z; As[ac + 3][ar + 32] = a1.w;
    *(float4*)&Bs[br][bc] = b0;
    *(float4*)&Bs[br + 16][bc] = b1;
    __syncthreads();
#pragma unroll
    for (int kk = 0; kk < BK; ++kk) {
      const float4 av = *(const float4*)&As[kk][i0];
      const float4 bv = *(const float4*)&Bs[kk][j0];
      const float a_[4] = {av.x, av.y, av.z, av.w};
      const float b_[4] = {bv.x, bv.y, bv.z, bv.w};
#pragma unroll
      for (int rr = 0; rr < 4; ++rr)
#pragma unroll
        for (int c = 0; c < 4; ++c)
          acc[rr][c] = fmaf(a_[rr], b_[c], acc[rr][c]);
    }
  }
#pragma unroll
  for (int rr = 0; rr < 4; ++rr) {
    float4 v; float* vp = &v.x;
#pragma unroll
    for (int c = 0; c < 4; ++c) {
      float x = acc[rr][c] + bias0[n0 + j0 + c];
      if (mode == MODE_RELU) x = fmaxf(x, 0.0f);
      vp[c] = x;
    }
    *(float4*)(C + (size_t)(m0 + i0 + rr) * ldc + n0 + j0) = v;
  }
}

__global__ __launch_bounds__(256) void tvec_k(
    const float* __restrict__ emb_w, const float* __restrict__ emb_b,
    float* __restrict__ tv)
{
  const int j = blockIdx.x * 256 + threadIdx.x;
  float s = emb_b[j];
#pragma unroll 8
  for (int k = 0; k < FHID; ++k)
    s = fmaf((float)k * (1.0f / 127.0f), emb_w[(size_t)(FHID + k) * HID + j], s);
  tv[j] = s;
}

// ---------------------------------------------------------------------------
extern "C" void kernel_launch(void* const* d_in, const int* in_sizes, int n_in,
                              void* d_out, int out_size, void* d_ws, size_t ws_size,
                              hipStream_t stream) {
  const float* coeffs    = (const float*)d_in[0];
  const float* dw        = (const float*)d_in[2];
  const float* f_ws      = (const float*)d_in[3];
  const float* f_bs      = (const float*)d_in[4];
  const float* g_ws      = (const float*)d_in[5];
  const float* g_bs      = (const float*)d_in[6];
  const float* initial_w = (const float*)d_in[7];
  const float* initial_b = (const float*)d_in[8];
  const float* lin_in_w  = (const float*)d_in[9];
  const float* lin_in_b  = (const float*)d_in[10];
  const float* emb_w     = (const float*)d_in[11];
  const float* emb_b     = (const float*)d_in[12];
  const float* samp_w    = (const float*)d_in[13];
  const float* samp_b    = (const float*)d_in[14];
  float* out = (float*)d_out;

  char* ws = (char*)d_ws;
  f16*   Bt0h = (f16*)(ws);                       // 4 MB [2048][1024]
  f16*   Bt0l = (f16*)(ws + (4u << 20));
  f16*   Bt1h = (f16*)(ws + (8u << 20));
  f16*   Bt1l = (f16*)(ws + (12u << 20));
  f16*   yh   = (f16*)(ws + (16u << 20));         // 2 MB
  f16*   yl   = (f16*)(ws + (18u << 20));
  f16*   hh   = (f16*)(ws + (20u << 20));         // 4 MB [1024][2048]
  f16*   hl   = (f16*)(ws + (24u << 20));
  float* y    = (float*)(ws + (28u << 20));       // 4 MB
  float* z1   = (float*)(ws + (32u << 20));       // 512 KB
  float* z2   = (float*)(ws + (33u << 20));       // 4 MB
  float* tv   = (float*)(ws + (37u << 20));       // 4 KB

  split_transpose_k<<<dim3(HID / 32, HID / 32, 4), dim3(32, 8), 0, stream>>>(
      f_ws, g_ws, Bt0h, Bt0l, Bt1h, Bt1l);

  y0_k<<<BATCH, 256, 0, stream>>>(coeffs, initial_w, initial_b, y, yh, yl);

  for (int k = 0; k < NSTEPS; ++k) {
    g1_k<<<512, 256, 0, stream>>>(yh, yl, Bt0h, Bt0l, f_bs, g_bs, hh, hl);
    g2u_k<<<512, 256, 0, stream>>>(hh, hl, Bt1h, Bt1l, f_bs + HID, g_bs + HID,
                                   dw + (size_t)k * BATCH * HID, y, yh, yl);
  }

  // decoder
  gemm_k<<<dim3(FHID / BN, BATCH / BM), 256, 0, stream>>>(
      y, HID, lin_in_w, FHID, lin_in_b, z1, FHID, HID, MODE_RELU);
  tvec_k<<<HID / 256, 256, 0, stream>>>(emb_w, emb_b, tv);
  gemm_k<<<dim3(HID / BN, BATCH / BM), 256, 0, stream>>>(
      z1, FHID, emb_w, HID, tv, z2, HID, FHID, MODE_RELU);
  gemm_k<<<dim3(FHID / BN, BATCH / BM), 256, 0, stream>>>(
      z2, HID, samp_w, FHID, samp_b, out, FHID, HID, MODE_LIN);
}